// Round 1
// baseline (3457.261 us; speedup 1.0000x reference)
//
#include <hip/hip_runtime.h>
#include <hip/hip_bf16.h>

typedef __hip_bfloat16 bf16;

#define BDIM 2048   // E*S
#define HDIM 512
#define LDIM 20
#define CDIM 32

__device__ __forceinline__ float sigm(float x) { return 1.0f / (1.0f + expf(-x)); }

// ---------------------------------------------------------------------------
// Generic fp32 GEMM: C[b][n] = sum_k A[b][k]*W[k][n] + bias[n]
// A: (2048,512) row-major, W: (512,512) row-major (pointer pre-offset), 64x64 tiles
// ---------------------------------------------------------------------------
__global__ __launch_bounds__(256) void k_gemm_bias(
    const float* __restrict__ A, const float* __restrict__ W,
    const float* __restrict__ bias, float* __restrict__ C)
{
    __shared__ float As[16][68];
    __shared__ float Ws[16][68];
    const int tid = threadIdx.x;
    const int tx = tid & 15, ty = tid >> 4;
    const int row0 = blockIdx.x * 64, col0 = blockIdx.y * 64;
    float acc[4][4] = {};
    for (int k0 = 0; k0 < 512; k0 += 16) {
        {
            int kk = tid & 15, m = tid >> 4;
#pragma unroll
            for (int r = 0; r < 4; ++r)
                As[kk][m + 16 * r] = A[(size_t)(row0 + m + 16 * r) * 512 + k0 + kk];
        }
        {
            int n = tid & 63, kk = tid >> 6;
#pragma unroll
            for (int r = 0; r < 4; ++r)
                Ws[kk + 4 * r][n] = W[(size_t)(k0 + kk + 4 * r) * 512 + col0 + n];
        }
        __syncthreads();
#pragma unroll
        for (int kk = 0; kk < 16; ++kk) {
            float4 av = *(const float4*)&As[kk][ty * 4];
            float4 wv = *(const float4*)&Ws[kk][tx * 4];
            float a_[4] = {av.x, av.y, av.z, av.w};
            float w_[4] = {wv.x, wv.y, wv.z, wv.w};
#pragma unroll
            for (int i = 0; i < 4; ++i)
#pragma unroll
                for (int j = 0; j < 4; ++j)
                    acc[i][j] = fmaf(a_[i], w_[j], acc[i][j]);
        }
        __syncthreads();
    }
#pragma unroll
    for (int i = 0; i < 4; ++i) {
        int b = row0 + ty * 4 + i;
#pragma unroll
        for (int j = 0; j < 4; ++j) {
            int n = col0 + tx * 4 + j;
            C[(size_t)b * 512 + n] = acc[i][j] + bias[n];
        }
    }
}

// ---------------------------------------------------------------------------
// GRU step part 1: r = sigmoid(gxr + h@Wr_h), z = sigmoid(gxz + h@Wz_h)
// writes rh = r*h and z
// ---------------------------------------------------------------------------
__global__ __launch_bounds__(256) void k_rz(
    const float* __restrict__ h, const float* __restrict__ Wr,
    const float* __restrict__ Wz, const float* __restrict__ gxr,
    const float* __restrict__ gxz, float* __restrict__ rh, float* __restrict__ zb)
{
    __shared__ float As[16][68];
    __shared__ float Rs[16][68];
    __shared__ float Zs[16][68];
    const int tid = threadIdx.x;
    const int tx = tid & 15, ty = tid >> 4;
    const int row0 = blockIdx.x * 64, col0 = blockIdx.y * 64;
    float accr[4][4] = {};
    float accz[4][4] = {};
    for (int k0 = 0; k0 < 512; k0 += 16) {
        {
            int kk = tid & 15, m = tid >> 4;
#pragma unroll
            for (int r = 0; r < 4; ++r)
                As[kk][m + 16 * r] = h[(size_t)(row0 + m + 16 * r) * 512 + k0 + kk];
        }
        {
            int n = tid & 63, kk = tid >> 6;
#pragma unroll
            for (int r = 0; r < 4; ++r) {
                Rs[kk + 4 * r][n] = Wr[(size_t)(k0 + kk + 4 * r) * 512 + col0 + n];
                Zs[kk + 4 * r][n] = Wz[(size_t)(k0 + kk + 4 * r) * 512 + col0 + n];
            }
        }
        __syncthreads();
#pragma unroll
        for (int kk = 0; kk < 16; ++kk) {
            float4 av = *(const float4*)&As[kk][ty * 4];
            float4 rv = *(const float4*)&Rs[kk][tx * 4];
            float4 zv = *(const float4*)&Zs[kk][tx * 4];
            float a_[4] = {av.x, av.y, av.z, av.w};
            float r_[4] = {rv.x, rv.y, rv.z, rv.w};
            float z_[4] = {zv.x, zv.y, zv.z, zv.w};
#pragma unroll
            for (int i = 0; i < 4; ++i)
#pragma unroll
                for (int j = 0; j < 4; ++j) {
                    accr[i][j] = fmaf(a_[i], r_[j], accr[i][j]);
                    accz[i][j] = fmaf(a_[i], z_[j], accz[i][j]);
                }
        }
        __syncthreads();
    }
#pragma unroll
    for (int i = 0; i < 4; ++i) {
        int b = row0 + ty * 4 + i;
#pragma unroll
        for (int j = 0; j < 4; ++j) {
            int n = col0 + tx * 4 + j;
            size_t idx = (size_t)b * 512 + n;
            float r = sigm(accr[i][j] + gxr[idx]);
            float z = sigm(accz[i][j] + gxz[idx]);
            float hv = h[idx];
            rh[idx] = r * hv;
            zb[idx] = z;
        }
    }
}

// ---------------------------------------------------------------------------
// GRU step part 2: n = tanh(gxn + rh@Wn_h); h = (1-z)*n + z*h; hs[t] = bf16(h)
// ---------------------------------------------------------------------------
__global__ __launch_bounds__(256) void k_nstep(
    const float* __restrict__ rh, const float* __restrict__ Wn,
    const float* __restrict__ gxn, const float* __restrict__ zb,
    float* __restrict__ h, bf16* __restrict__ hs_t)
{
    __shared__ float As[16][68];
    __shared__ float Ws[16][68];
    const int tid = threadIdx.x;
    const int tx = tid & 15, ty = tid >> 4;
    const int row0 = blockIdx.x * 64, col0 = blockIdx.y * 64;
    float acc[4][4] = {};
    for (int k0 = 0; k0 < 512; k0 += 16) {
        {
            int kk = tid & 15, m = tid >> 4;
#pragma unroll
            for (int r = 0; r < 4; ++r)
                As[kk][m + 16 * r] = rh[(size_t)(row0 + m + 16 * r) * 512 + k0 + kk];
        }
        {
            int n = tid & 63, kk = tid >> 6;
#pragma unroll
            for (int r = 0; r < 4; ++r)
                Ws[kk + 4 * r][n] = Wn[(size_t)(k0 + kk + 4 * r) * 512 + col0 + n];
        }
        __syncthreads();
#pragma unroll
        for (int kk = 0; kk < 16; ++kk) {
            float4 av = *(const float4*)&As[kk][ty * 4];
            float4 wv = *(const float4*)&Ws[kk][tx * 4];
            float a_[4] = {av.x, av.y, av.z, av.w};
            float w_[4] = {wv.x, wv.y, wv.z, wv.w};
#pragma unroll
            for (int i = 0; i < 4; ++i)
#pragma unroll
                for (int j = 0; j < 4; ++j)
                    acc[i][j] = fmaf(a_[i], w_[j], acc[i][j]);
        }
        __syncthreads();
    }
#pragma unroll
    for (int i = 0; i < 4; ++i) {
        int b = row0 + ty * 4 + i;
#pragma unroll
        for (int j = 0; j < 4; ++j) {
            int n = col0 + tx * 4 + j;
            size_t idx = (size_t)b * 512 + n;
            float nv = tanhf(acc[i][j] + gxn[idx]);
            float z = zb[idx];
            float hn = (1.0f - z) * nv + z * h[idx];
            h[idx] = hn;
            hs_t[idx] = (bf16)hn;
        }
    }
}

// ---------------------------------------------------------------------------
// Transpose conv weights w[co][ci][tap] -> wt[g][tap][ci][co] (coalesced co)
// ---------------------------------------------------------------------------
__global__ __launch_bounds__(256) void k_prep_wt(
    const float* __restrict__ w1, const float* __restrict__ w3,
    const float* __restrict__ w5, const float* __restrict__ w7,
    float* __restrict__ wt)
{
    int idx = blockIdx.x * 256 + threadIdx.x;  // 0 .. 1048575
    int g, rel, base;
    if (idx < 65536)       { g = 0; base = 0;      }
    else if (idx < 262144) { g = 1; base = 65536;  }
    else if (idx < 589824) { g = 2; base = 262144; }
    else                   { g = 3; base = 589824; }
    rel = idx - base;
    int k = 2 * g + 1;
    int co = rel & 127;
    int t2 = rel >> 7;
    int ci = t2 & 511;
    int tap = t2 >> 9;
    const float* w = (g == 0) ? w1 : (g == 1) ? w3 : (g == 2) ? w5 : w7;
    wt[idx] = w[((size_t)co * 512 + ci) * k + tap];
}

// ---------------------------------------------------------------------------
// Multiscale conv as GEMM with tap accumulation + bias + PReLU -> y bf16 (B,L,H)
// grid: (btile=16, group=4, l=20); block 256; 128x128 tile, 8x8/thread
// ---------------------------------------------------------------------------
__global__ __launch_bounds__(256) void k_conv(
    const bf16* __restrict__ hs, const float* __restrict__ wt,
    const float* __restrict__ b1, const float* __restrict__ b3,
    const float* __restrict__ b5, const float* __restrict__ b7,
    const float* __restrict__ pa, bf16* __restrict__ y)
{
    __shared__ float As[16][136];
    __shared__ float Ws[16][136];
    const int tid = threadIdx.x;
    const int tx = tid & 15, ty = tid >> 4;
    const int btile = blockIdx.x, g = blockIdx.y, l = blockIdx.z;
    const int row0 = btile * 128, co0 = g * 128;
    const int k = 2 * g + 1, p = g;
    const int offs[4] = {0, 65536, 262144, 589824};
    const float* Wg = wt + offs[g];
    float acc[8][8] = {};
    for (int tap = 0; tap < k; ++tap) {
        int li = l + tap - p;
        if (li < 0 || li >= LDIM) continue;
        const bf16* Ablk = hs + (size_t)li * BDIM * HDIM;
        for (int k0 = 0; k0 < 512; k0 += 16) {
            {
                int kk = tid & 15, m = tid >> 4;
#pragma unroll
                for (int r = 0; r < 8; ++r)
                    As[kk][m + 16 * r] =
                        __bfloat162float(Ablk[(size_t)(row0 + m + 16 * r) * 512 + k0 + kk]);
            }
            {
                int n = tid & 127, kk = tid >> 7;
#pragma unroll
                for (int r = 0; r < 8; ++r)
                    Ws[kk + 2 * r][n] =
                        Wg[(size_t)(tap * 512 + k0 + kk + 2 * r) * 128 + n];
            }
            __syncthreads();
#pragma unroll
            for (int kk = 0; kk < 16; ++kk) {
                float4 a0 = *(const float4*)&As[kk][ty * 4];
                float4 a1 = *(const float4*)&As[kk][64 + ty * 4];
                float4 w0 = *(const float4*)&Ws[kk][tx * 4];
                float4 w1 = *(const float4*)&Ws[kk][64 + tx * 4];
                float a_[8] = {a0.x, a0.y, a0.z, a0.w, a1.x, a1.y, a1.z, a1.w};
                float w_[8] = {w0.x, w0.y, w0.z, w0.w, w1.x, w1.y, w1.z, w1.w};
#pragma unroll
                for (int i = 0; i < 8; ++i)
#pragma unroll
                    for (int j = 0; j < 8; ++j)
                        acc[i][j] = fmaf(a_[i], w_[j], acc[i][j]);
            }
            __syncthreads();
        }
    }
    const float* bp = (g == 0) ? b1 : (g == 1) ? b3 : (g == 2) ? b5 : b7;
    const float a = *pa;
#pragma unroll
    for (int i = 0; i < 8; ++i) {
        int b = row0 + ((i < 4) ? (ty * 4 + i) : (64 + ty * 4 + i - 4));
#pragma unroll
        for (int j = 0; j < 8; ++j) {
            int col = (j < 4) ? (tx * 4 + j) : (64 + tx * 4 + j - 4);
            float v = acc[i][j] + bp[col];
            v = (v >= 0.0f) ? v : a * v;
            y[((size_t)b * LDIM + l) * 512 + co0 + col] = (bf16)v;
        }
    }
}

// ---------------------------------------------------------------------------
// Head: per (b,l): mu/std projections (K=512 -> C=32), sample, tanh, log_prob
// block = 64 threads (1 wave), grid = B*L
// ---------------------------------------------------------------------------
__global__ __launch_bounds__(64) void k_head(
    const bf16* __restrict__ y, const float* __restrict__ Wmu,
    const float* __restrict__ bmu, const float* __restrict__ Wstd,
    const float* __restrict__ bstd, const float* __restrict__ eps,
    float* __restrict__ out_comm, float* __restrict__ lpsum)
{
    __shared__ float ys[512];
    const int bid = blockIdx.x;  // b*20+l
    const int tid = threadIdx.x;
    for (int i = tid; i < 512; i += 64)
        ys[i] = __bfloat162float(y[(size_t)bid * 512 + i]);
    __syncthreads();
    const int c = tid & 31;
    const int which = tid >> 5;
    const float* Wp = which ? Wstd : Wmu;
    float acc = 0.0f;
#pragma unroll 8
    for (int kI = 0; kI < 512; ++kI)
        acc = fmaf(ys[kI], Wp[(size_t)kI * 32 + c], acc);
    acc += which ? bstd[c] : bmu[c];
    float other = __shfl(acc, tid + 32, 64);
    if (tid < 32) {
        float mu = acc;
        float sraw = other;
        float sp = (sraw > 20.0f) ? sraw : log1pf(expf(sraw));
        float sd = fminf(fmaxf(sp, 2.0611536e-09f), 7.389056f);
        float e = eps[(size_t)bid * 32 + c];
        float comm = fmaf(e, sd, mu);
        float t = tanhf(comm);
        out_comm[(size_t)bid * 32 + c] = t;
        float lp = -0.5f * e * e - logf(sd) - 0.91893853320467274f
                   - logf(1.0f - t * t + 1e-6f);
#pragma unroll
        for (int off = 16; off > 0; off >>= 1)
            lp += __shfl_down(lp, off, 64);
        if (tid == 0) lpsum[bid] = lp;
    }
}

__global__ __launch_bounds__(256) void k_final(const float* __restrict__ lpsum,
                                               float* __restrict__ out2)
{
    int b = blockIdx.x * 256 + threadIdx.x;
    if (b < BDIM) {
        float s = 0.0f;
#pragma unroll
        for (int i = 0; i < LDIM; ++i) s += lpsum[b * LDIM + i];
        out2[b] = s * (1.0f / (LDIM * CDIM));
    }
}

// ---------------------------------------------------------------------------
extern "C" void kernel_launch(void* const* d_in, const int* in_sizes, int n_in,
                              void* d_out, int out_size, void* d_ws, size_t ws_size,
                              hipStream_t stream)
{
    const float* x    = (const float*)d_in[0];
    const float* Wr   = (const float*)d_in[1];
    const float* br   = (const float*)d_in[2];
    const float* Wz   = (const float*)d_in[3];
    const float* bz   = (const float*)d_in[4];
    const float* Wn   = (const float*)d_in[5];
    const float* bn   = (const float*)d_in[6];
    const float* w1   = (const float*)d_in[7];
    const float* b1   = (const float*)d_in[8];
    const float* w3   = (const float*)d_in[9];
    const float* b3   = (const float*)d_in[10];
    const float* w5   = (const float*)d_in[11];
    const float* b5   = (const float*)d_in[12];
    const float* w7   = (const float*)d_in[13];
    const float* b7   = (const float*)d_in[14];
    const float* pa   = (const float*)d_in[15];
    const float* Wmu  = (const float*)d_in[16];
    const float* bmu  = (const float*)d_in[17];
    const float* Wstd = (const float*)d_in[18];
    const float* bstd = (const float*)d_in[19];
    const float* eps  = (const float*)d_in[20];

    char* cur = (char*)d_ws;
    auto alloc = [&](size_t bytes) -> void* {
        void* r = (void*)cur;
        cur += (bytes + 255) & ~(size_t)255;
        return r;
    };
    const size_t BH = (size_t)BDIM * HDIM;
    float* gxr   = (float*)alloc(BH * 4);
    float* gxz   = (float*)alloc(BH * 4);
    float* gxn   = (float*)alloc(BH * 4);
    float* h     = (float*)alloc(BH * 4);
    float* rh    = (float*)alloc(BH * 4);
    float* zb    = (float*)alloc(BH * 4);
    float* wt    = (float*)alloc(1048576 * 4);
    bf16*  hs    = (bf16*)alloc(BH * LDIM * 2);
    bf16*  ybuf  = (bf16*)alloc(BH * LDIM * 2);
    float* lpsum = (float*)alloc((size_t)BDIM * LDIM * 4);

    hipMemsetAsync(h, 0, BH * 4, stream);
    k_prep_wt<<<4096, 256, 0, stream>>>(w1, w3, w5, w7, wt);

    dim3 gg(32, 8);
    k_gemm_bias<<<gg, 256, 0, stream>>>(x, Wr, br, gxr);
    k_gemm_bias<<<gg, 256, 0, stream>>>(x, Wz, bz, gxz);
    k_gemm_bias<<<gg, 256, 0, stream>>>(x, Wn, bn, gxn);

    const float* Wrh = Wr + 512 * 512;
    const float* Wzh = Wz + 512 * 512;
    const float* Wnh = Wn + 512 * 512;
    for (int t = 0; t < LDIM; ++t) {
        k_rz<<<gg, 256, 0, stream>>>(h, Wrh, Wzh, gxr, gxz, rh, zb);
        k_nstep<<<gg, 256, 0, stream>>>(rh, Wnh, gxn, zb, h, hs + (size_t)t * BH);
    }

    k_conv<<<dim3(16, 4, 20), 256, 0, stream>>>(hs, wt, b1, b3, b5, b7, pa, ybuf);

    float* out_comm = (float*)d_out;
    float* out_lp   = (float*)d_out + (size_t)BDIM * LDIM * CDIM;
    k_head<<<BDIM * LDIM, 64, 0, stream>>>(ybuf, Wmu, bmu, Wstd, bstd, eps,
                                           out_comm, lpsum);
    k_final<<<8, 256, 0, stream>>>(lpsum, out_lp);
}

// Round 2
// 1934.584 us; speedup vs baseline: 1.7871x; 1.7871x over previous
//
#include <hip/hip_runtime.h>
#include <hip/hip_bf16.h>

typedef __hip_bfloat16 bf16;
typedef short short8 __attribute__((ext_vector_type(8)));
typedef float floatx4 __attribute__((ext_vector_type(4)));

#define BDIM 2048   // E*S
#define HDIM 512
#define LDIM 20
#define CDIM 32
#define LSTR 40     // LDS row stride in bf16 elements (32 + 8 pad, keeps 16B align)

__device__ __forceinline__ float sigm(float x) { return 1.0f / (1.0f + expf(-x)); }

// ---------------------------------------------------------------------------
// Core 128x128 bf16 MFMA tile: C += A(128xK) @ B(Kx128), A row-major [m][k],
// Bt row-major transposed [n][k]. 256 threads = 4 waves in 2x2, each 64x64.
// acc fragment (i,j): rows i*16+quad*4+reg, cols j*16+(lane&15) within wave tile.
// ---------------------------------------------------------------------------
__device__ __forceinline__ void gemm_tile_k(
    const short* __restrict__ A, int lda,
    const short* __restrict__ Bt, int ldb,
    int K, short* lds, floatx4 (&acc)[4][4], int tid)
{
    short* As = lds;              // [128][LSTR]
    short* Bs = lds + 128 * LSTR; // [128][LSTR]
    const int wave = tid >> 6, lane = tid & 63;
    const int wm = wave & 1, wn = wave >> 1;
    const int m16 = lane & 15, quad = lane >> 4;
    const int r0 = tid >> 2;          // 0..63
    const int koff = (tid & 3) * 8;   // 0,8,16,24

    for (int k0 = 0; k0 < K; k0 += 32) {
        short8 a0 = *(const short8*)(A + (size_t)r0 * lda + k0 + koff);
        short8 a1 = *(const short8*)(A + (size_t)(r0 + 64) * lda + k0 + koff);
        short8 b0 = *(const short8*)(Bt + (size_t)r0 * ldb + k0 + koff);
        short8 b1 = *(const short8*)(Bt + (size_t)(r0 + 64) * ldb + k0 + koff);
        __syncthreads();
        *(short8*)(As + r0 * LSTR + koff) = a0;
        *(short8*)(As + (r0 + 64) * LSTR + koff) = a1;
        *(short8*)(Bs + r0 * LSTR + koff) = b0;
        *(short8*)(Bs + (r0 + 64) * LSTR + koff) = b1;
        __syncthreads();
        short8 af[4], bfr[4];
#pragma unroll
        for (int i = 0; i < 4; ++i)
            af[i] = *(short8*)(As + (wm * 64 + i * 16 + m16) * LSTR + quad * 8);
#pragma unroll
        for (int j = 0; j < 4; ++j)
            bfr[j] = *(short8*)(Bs + (wn * 64 + j * 16 + m16) * LSTR + quad * 8);
#pragma unroll
        for (int i = 0; i < 4; ++i)
#pragma unroll
            for (int j = 0; j < 4; ++j)
                acc[i][j] = __builtin_amdgcn_mfma_f32_16x16x32_bf16(
                    af[i], bfr[j], acc[i][j], 0, 0, 0);
    }
}

// ---------------------------------------------------------------------------
// Prep: fp32 x -> bf16
// ---------------------------------------------------------------------------
__global__ __launch_bounds__(256) void k_prep_xb(const float* __restrict__ x,
                                                 bf16* __restrict__ xb)
{
    int i = blockIdx.x * 256 + threadIdx.x;
    xb[i] = (bf16)x[i];
}

// ---------------------------------------------------------------------------
// Prep: transpose fp32 [512 k][512 n] -> bf16 [n][k]
// ---------------------------------------------------------------------------
__global__ __launch_bounds__(256) void k_transpose_512(const float* __restrict__ src,
                                                       bf16* __restrict__ dst)
{
    __shared__ float tile[32][33];
    int tx = threadIdx.x & 31, ty = threadIdx.x >> 5;
    int k0 = blockIdx.x * 32, n0 = blockIdx.y * 32;
#pragma unroll
    for (int i = 0; i < 32; i += 8)
        tile[ty + i][tx] = src[(size_t)(k0 + ty + i) * 512 + n0 + tx];
    __syncthreads();
#pragma unroll
    for (int i = 0; i < 32; i += 8)
        dst[(size_t)(n0 + ty + i) * 512 + k0 + tx] = (bf16)tile[tx][ty + i];
}

// ---------------------------------------------------------------------------
// Prep: conv weights w[co][ci][tap] -> wt[g][tap][co][ci] bf16
// ---------------------------------------------------------------------------
__global__ __launch_bounds__(256) void k_prep_wc(
    const float* __restrict__ w1, const float* __restrict__ w3,
    const float* __restrict__ w5, const float* __restrict__ w7,
    bf16* __restrict__ wt)
{
    int idx = blockIdx.x * 256 + threadIdx.x;  // 0 .. 1048575
    int g, base;
    if (idx < 65536)       { g = 0; base = 0;      }
    else if (idx < 262144) { g = 1; base = 65536;  }
    else if (idx < 589824) { g = 2; base = 262144; }
    else                   { g = 3; base = 589824; }
    int rel = idx - base;
    int k = 2 * g + 1;
    int ci = rel & 511;
    int t2 = rel >> 9;
    int co = t2 & 127;
    int tap = t2 >> 7;
    const float* w = (g == 0) ? w1 : (g == 1) ? w3 : (g == 2) ? w5 : w7;
    wt[idx] = (bf16)w[((size_t)co * 512 + ci) * k + tap];
}

// ---------------------------------------------------------------------------
// gx = x @ [Wr_x | Wz_x | Wn_x] + [br|bz|bn]   (M=2048, N=1536, K=512)
// ---------------------------------------------------------------------------
__global__ __launch_bounds__(256) void k_gx(
    const bf16* __restrict__ xb, const bf16* __restrict__ Wx_t,
    const float* __restrict__ br, const float* __restrict__ bz,
    const float* __restrict__ bn, float* __restrict__ gxall)
{
    __shared__ short lds[2 * 128 * LSTR];
    const int tid = threadIdx.x;
    const int row0 = blockIdx.x * 128, col0 = blockIdx.y * 128;
    floatx4 acc[4][4];
#pragma unroll
    for (int i = 0; i < 4; ++i)
#pragma unroll
        for (int j = 0; j < 4; ++j) acc[i][j] = (floatx4)0.0f;
    gemm_tile_k((const short*)xb + (size_t)row0 * 512, 512,
                (const short*)Wx_t + (size_t)col0 * 512, 512, 512, lds, acc, tid);
    const int wave = tid >> 6, lane = tid & 63;
    const int wm = wave & 1, wn = wave >> 1;
    const int m16 = lane & 15, quad = lane >> 4;
#pragma unroll
    for (int i = 0; i < 4; ++i)
#pragma unroll
        for (int j = 0; j < 4; ++j)
#pragma unroll
            for (int reg = 0; reg < 4; ++reg) {
                int b = row0 + wm * 64 + i * 16 + quad * 4 + reg;
                int n = col0 + wn * 64 + j * 16 + m16;
                float bias = (n < 512) ? br[n] : (n < 1024) ? bz[n - 512] : bn[n - 1024];
                gxall[(size_t)b * 1536 + n] = acc[i][j][reg] + bias;
            }
}

// ---------------------------------------------------------------------------
// GRU r,z: pre = h_prev @ [Wr_h | Wz_h] + gx; r-cols write rh=r*h, z-cols write z
// ---------------------------------------------------------------------------
__global__ __launch_bounds__(256) void k_rz(
    const bf16* __restrict__ hprev, const bf16* __restrict__ Wrz_t,
    const float* __restrict__ gxall, const float* __restrict__ h32,
    bf16* __restrict__ rhb, bf16* __restrict__ zb, int K)
{
    __shared__ short lds[2 * 128 * LSTR];
    const int tid = threadIdx.x;
    const int row0 = blockIdx.x * 128, col0 = blockIdx.y * 128;
    floatx4 acc[4][4];
#pragma unroll
    for (int i = 0; i < 4; ++i)
#pragma unroll
        for (int j = 0; j < 4; ++j) acc[i][j] = (floatx4)0.0f;
    gemm_tile_k((const short*)hprev + (size_t)row0 * 512, 512,
                (const short*)Wrz_t + (size_t)col0 * 512, 512, K, lds, acc, tid);
    const int wave = tid >> 6, lane = tid & 63;
    const int wm = wave & 1, wn = wave >> 1;
    const int m16 = lane & 15, quad = lane >> 4;
#pragma unroll
    for (int i = 0; i < 4; ++i)
#pragma unroll
        for (int j = 0; j < 4; ++j)
#pragma unroll
            for (int reg = 0; reg < 4; ++reg) {
                int b = row0 + wm * 64 + i * 16 + quad * 4 + reg;
                int n = col0 + wn * 64 + j * 16 + m16;
                float v = sigm(acc[i][j][reg] + gxall[(size_t)b * 1536 + n]);
                if (n < 512)
                    rhb[(size_t)b * 512 + n] = (bf16)(v * h32[(size_t)b * 512 + n]);
                else
                    zb[(size_t)b * 512 + (n - 512)] = (bf16)v;
            }
}

// ---------------------------------------------------------------------------
// GRU n + state update: n = tanh(rh @ Wn_h + gx_n); h = (1-z)n + z*h; hs[t]=bf16(h)
// ---------------------------------------------------------------------------
__global__ __launch_bounds__(256) void k_n(
    const bf16* __restrict__ rhb, const bf16* __restrict__ Wn_t,
    const float* __restrict__ gxall, const bf16* __restrict__ zb,
    float* __restrict__ h32, bf16* __restrict__ hs_t, int K)
{
    __shared__ short lds[2 * 128 * LSTR];
    const int tid = threadIdx.x;
    const int row0 = blockIdx.x * 128, col0 = blockIdx.y * 128;
    floatx4 acc[4][4];
#pragma unroll
    for (int i = 0; i < 4; ++i)
#pragma unroll
        for (int j = 0; j < 4; ++j) acc[i][j] = (floatx4)0.0f;
    gemm_tile_k((const short*)rhb + (size_t)row0 * 512, 512,
                (const short*)Wn_t + (size_t)col0 * 512, 512, K, lds, acc, tid);
    const int wave = tid >> 6, lane = tid & 63;
    const int wm = wave & 1, wn = wave >> 1;
    const int m16 = lane & 15, quad = lane >> 4;
#pragma unroll
    for (int i = 0; i < 4; ++i)
#pragma unroll
        for (int j = 0; j < 4; ++j)
#pragma unroll
            for (int reg = 0; reg < 4; ++reg) {
                int b = row0 + wm * 64 + i * 16 + quad * 4 + reg;
                int n = col0 + wn * 64 + j * 16 + m16;
                size_t idx = (size_t)b * 512 + n;
                float nv = tanhf(acc[i][j][reg] + gxall[(size_t)b * 1536 + 1024 + n]);
                float z = __bfloat162float(zb[idx]);
                float hn = (1.0f - z) * nv + z * h32[idx];
                h32[idx] = hn;
                hs_t[idx] = (bf16)hn;
            }
}

// ---------------------------------------------------------------------------
// Multiscale conv as MFMA GEMM + bias + PReLU -> y bf16 (B, L, 512)
// grid (btile 16, g 4, l 20)
// ---------------------------------------------------------------------------
__global__ __launch_bounds__(256) void k_conv(
    const bf16* __restrict__ hs, const bf16* __restrict__ Wc_t,
    const float* __restrict__ b1, const float* __restrict__ b3,
    const float* __restrict__ b5, const float* __restrict__ b7,
    const float* __restrict__ pa, bf16* __restrict__ y)
{
    __shared__ short lds[2 * 128 * LSTR];
    const int tid = threadIdx.x;
    const int btile = blockIdx.x, g = blockIdx.y, l = blockIdx.z;
    const int row0 = btile * 128;
    const int ktap = 2 * g + 1, p = g;
    const int offs[4] = {0, 65536, 262144, 589824};
    const short* Wg = (const short*)Wc_t + offs[g];
    floatx4 acc[4][4];
#pragma unroll
    for (int i = 0; i < 4; ++i)
#pragma unroll
        for (int j = 0; j < 4; ++j) acc[i][j] = (floatx4)0.0f;
    for (int tap = 0; tap < ktap; ++tap) {
        int li = l + tap - p;
        if (li < 0 || li >= LDIM) continue;
        gemm_tile_k((const short*)hs + (size_t)li * BDIM * HDIM + (size_t)row0 * 512, 512,
                    Wg + (size_t)tap * 128 * 512, 512, 512, lds, acc, tid);
    }
    const float* bp = (g == 0) ? b1 : (g == 1) ? b3 : (g == 2) ? b5 : b7;
    const float a = *pa;
    const int wave = tid >> 6, lane = tid & 63;
    const int wm = wave & 1, wn = wave >> 1;
    const int m16 = lane & 15, quad = lane >> 4;
#pragma unroll
    for (int i = 0; i < 4; ++i)
#pragma unroll
        for (int j = 0; j < 4; ++j)
#pragma unroll
            for (int reg = 0; reg < 4; ++reg) {
                int b = row0 + wm * 64 + i * 16 + quad * 4 + reg;
                int col = wn * 64 + j * 16 + m16;   // 0..127 within group
                float v = acc[i][j][reg] + bp[col];
                v = (v >= 0.0f) ? v : a * v;
                y[((size_t)b * LDIM + l) * 512 + g * 128 + col] = (bf16)v;
            }
}

// ---------------------------------------------------------------------------
// Head: per (b,l): mu/std projections (K=512 -> C=32), sample, tanh, log_prob
// ---------------------------------------------------------------------------
__global__ __launch_bounds__(64) void k_head(
    const bf16* __restrict__ y, const float* __restrict__ Wmu,
    const float* __restrict__ bmu, const float* __restrict__ Wstd,
    const float* __restrict__ bstd, const float* __restrict__ eps,
    float* __restrict__ out_comm, float* __restrict__ lpsum)
{
    __shared__ float ys[512];
    const int bid = blockIdx.x;  // b*20+l
    const int tid = threadIdx.x;
    for (int i = tid; i < 512; i += 64)
        ys[i] = __bfloat162float(y[(size_t)bid * 512 + i]);
    __syncthreads();
    const int c = tid & 31;
    const int which = tid >> 5;
    const float* Wp = which ? Wstd : Wmu;
    float acc = 0.0f;
#pragma unroll 8
    for (int kI = 0; kI < 512; ++kI)
        acc = fmaf(ys[kI], Wp[(size_t)kI * 32 + c], acc);
    acc += which ? bstd[c] : bmu[c];
    float other = __shfl(acc, tid + 32, 64);
    if (tid < 32) {
        float mu = acc;
        float sraw = other;
        float sp = (sraw > 20.0f) ? sraw : log1pf(expf(sraw));
        float sd = fminf(fmaxf(sp, 2.0611536e-09f), 7.389056f);
        float e = eps[(size_t)bid * 32 + c];
        float comm = fmaf(e, sd, mu);
        float t = tanhf(comm);
        out_comm[(size_t)bid * 32 + c] = t;
        float lp = -0.5f * e * e - logf(sd) - 0.91893853320467274f
                   - logf(1.0f - t * t + 1e-6f);
#pragma unroll
        for (int off = 16; off > 0; off >>= 1)
            lp += __shfl_down(lp, off, 64);
        if (tid == 0) lpsum[bid] = lp;
    }
}

__global__ __launch_bounds__(256) void k_final(const float* __restrict__ lpsum,
                                               float* __restrict__ out2)
{
    int b = blockIdx.x * 256 + threadIdx.x;
    if (b < BDIM) {
        float s = 0.0f;
#pragma unroll
        for (int i = 0; i < LDIM; ++i) s += lpsum[b * LDIM + i];
        out2[b] = s * (1.0f / (LDIM * CDIM));
    }
}

// ---------------------------------------------------------------------------
extern "C" void kernel_launch(void* const* d_in, const int* in_sizes, int n_in,
                              void* d_out, int out_size, void* d_ws, size_t ws_size,
                              hipStream_t stream)
{
    const float* x    = (const float*)d_in[0];
    const float* Wr   = (const float*)d_in[1];
    const float* br   = (const float*)d_in[2];
    const float* Wz   = (const float*)d_in[3];
    const float* bz   = (const float*)d_in[4];
    const float* Wn   = (const float*)d_in[5];
    const float* bn   = (const float*)d_in[6];
    const float* w1   = (const float*)d_in[7];
    const float* b1   = (const float*)d_in[8];
    const float* w3   = (const float*)d_in[9];
    const float* b3   = (const float*)d_in[10];
    const float* w5   = (const float*)d_in[11];
    const float* b5   = (const float*)d_in[12];
    const float* w7   = (const float*)d_in[13];
    const float* b7   = (const float*)d_in[14];
    const float* pa   = (const float*)d_in[15];
    const float* Wmu  = (const float*)d_in[16];
    const float* bmu  = (const float*)d_in[17];
    const float* Wstd = (const float*)d_in[18];
    const float* bstd = (const float*)d_in[19];
    const float* eps  = (const float*)d_in[20];

    char* cur = (char*)d_ws;
    auto alloc = [&](size_t bytes) -> void* {
        void* r = (void*)cur;
        cur += (bytes + 255) & ~(size_t)255;
        return r;
    };
    const size_t BH = (size_t)BDIM * HDIM;
    float* gxall = (float*)alloc((size_t)BDIM * 1536 * 4);
    float* h32   = (float*)alloc(BH * 4);
    bf16*  zb    = (bf16*)alloc(BH * 2);
    bf16*  rhb   = (bf16*)alloc(BH * 2);
    bf16*  xb    = (bf16*)alloc(BH * 2);
    bf16*  hs    = (bf16*)alloc(BH * LDIM * 2);
    bf16*  ybuf  = (bf16*)alloc(BH * LDIM * 2);
    bf16*  Wx_t  = (bf16*)alloc((size_t)1536 * 512 * 2);
    bf16*  Wrz_t = (bf16*)alloc((size_t)1024 * 512 * 2);
    bf16*  Wn_t  = (bf16*)alloc((size_t)512 * 512 * 2);
    bf16*  Wc_t  = (bf16*)alloc((size_t)1048576 * 2);
    float* lpsum = (float*)alloc((size_t)BDIM * LDIM * 4);

    hipMemsetAsync(h32, 0, BH * 4, stream);
    k_prep_xb<<<4096, 256, 0, stream>>>(x, xb);
    dim3 tg(16, 16);
    k_transpose_512<<<tg, 256, 0, stream>>>(Wr, Wx_t);                    // x-half of Wr
    k_transpose_512<<<tg, 256, 0, stream>>>(Wz, Wx_t + 262144);
    k_transpose_512<<<tg, 256, 0, stream>>>(Wn, Wx_t + 524288);
    k_transpose_512<<<tg, 256, 0, stream>>>(Wr + 262144, Wrz_t);          // h-half of Wr
    k_transpose_512<<<tg, 256, 0, stream>>>(Wz + 262144, Wrz_t + 262144);
    k_transpose_512<<<tg, 256, 0, stream>>>(Wn + 262144, Wn_t);
    k_prep_wc<<<4096, 256, 0, stream>>>(w1, w3, w5, w7, Wc_t);

    k_gx<<<dim3(16, 12), 256, 0, stream>>>(xb, Wx_t, br, bz, bn, gxall);

    for (int t = 0; t < LDIM; ++t) {
        const bf16* hprev = (t == 0) ? hs : hs + (size_t)(t - 1) * BH;
        int K = (t == 0) ? 0 : 512;
        k_rz<<<dim3(16, 8), 256, 0, stream>>>(hprev, Wrz_t, gxall, h32, rhb, zb, K);
        k_n<<<dim3(16, 4), 256, 0, stream>>>(rhb, Wn_t, gxall, zb, h32,
                                             hs + (size_t)t * BH, K);
    }

    k_conv<<<dim3(16, 4, 20), 256, 0, stream>>>(hs, Wc_t, b1, b3, b5, b7, pa, ybuf);

    float* out_comm = (float*)d_out;
    float* out_lp   = (float*)d_out + (size_t)BDIM * LDIM * CDIM;
    k_head<<<BDIM * LDIM, 64, 0, stream>>>(ybuf, Wmu, bmu, Wstd, bstd, eps,
                                           out_comm, lpsum);
    k_final<<<8, 256, 0, stream>>>(lpsum, out_lp);
}